// Round 10
// baseline (7895.153 us; speedup 1.0000x reference)
//
#include <hip/hip_runtime.h>
#include <math.h>

// EncoderDecoderAttentionModel: B=64, T=256, H=D=256, L=3, NSTEPS=25, C=32000
#define TT    256
#define NB    64
#define HH    256
#define NSTEP 25
#define NCLS  32000
#define PADI  3
#define RING  4

// ---------------- static device scratch ----------------
__device__ __align__(16) float g_hring[3][RING][NB][HH]; // encoder h ring (sc1 in k_enc)
__device__ __align__(16) float g_enchid[TT][NB][HH];     // plain (cross-kernel)
__device__ __align__(16) float g_kp[NB][TT][HH];
__device__ __align__(16) float g_vp[NB][TT][HH];
__device__ __align__(16) float g_cfin[3][NB][HH];
__device__ __align__(16) float g_hdec[2][3][NB][HH];     // decoder h ping-pong (plain)
__device__ __align__(16) float g_cdec[3][NB][HH];        // decoder c state (plain)
__device__ __align__(16) float g_z0[NB][512];            // [embed ; ctx] (plain)
__device__ float    g_wmax[256][NB];
__device__ int      g_wmaxi[256][NB];
__device__ int      g_len[NB];
__device__ unsigned g_earr[3][64];                       // k_enc per-layer arrive flags
__device__ unsigned g_erel[3][64];                       // per-layer release, 4 lines at [l][16i]

__device__ __forceinline__ float sigf(float v){ return 1.0f / (1.0f + expf(-v)); }

#define SCOPE_AG __HIP_MEMORY_SCOPE_AGENT
typedef unsigned long long u64;
__device__ __forceinline__ float2 ld2(const float* p){
  u64 v = __hip_atomic_load((const u64*)p, __ATOMIC_RELAXED, SCOPE_AG);
  float2 r; __builtin_memcpy(&r, &v, 8); return r;
}
__device__ __forceinline__ void  stc(float* p, float v){ __hip_atomic_store(p, v, __ATOMIC_RELAXED, SCOPE_AG); }
__device__ __forceinline__ unsigned ldu(const unsigned* p){ return __hip_atomic_load(p, __ATOMIC_RELAXED, SCOPE_AG); }
__device__ __forceinline__ void  stu(unsigned* p, unsigned v){ __hip_atomic_store(p, v, __ATOMIC_RELAXED, SCOPE_AG); }

#define DOT4(a_, x_, w_) (a_) += (x_).x*(w_).x + (x_).y*(w_).y + (x_).z*(w_).z + (x_).w*(w_).w

// ---------------- k_init: flags, ring seed, lengths ----------------
__global__ void __launch_bounds__(256) k_init(const int* __restrict__ p_x){
  const int blk = blockIdx.x, tid = threadIdx.x;
  if (blk < 192){
    int idx = blk*256 + tid;                 // 49152 = 3*64*256 (ring slot RING-1)
    int l = idx >> 14, rem = idx & 16383;
    g_hring[l][RING-1][rem >> 8][rem & 255] = 0.f;
  } else {
    __shared__ int s_c[4];
    int b = blk - 192;
    int cnt = (p_x[b*TT + tid] != PADI) ? 1 : 0;
    #pragma unroll
    for (int m = 1; m < 64; m <<= 1) cnt += __shfl_xor(cnt, m);
    if ((tid & 63) == 0) s_c[tid >> 6] = cnt;
    __syncthreads();
    if (tid == 0) g_len[b] = s_c[0] + s_c[1] + s_c[2] + s_c[3];
  }
  if (blk == 0 && tid < 192){
    ((unsigned*)g_earr)[tid] = 0u;
    ((unsigned*)g_erel)[tid] = 0u;
  }
}

// ---------------- k_enc: 3-layer pipelined encoder ----------------
// R8-proven sync skeleton (tid-0 rel poll at top; master-gather arrive at bottom).
// R9 compute blocking: thread = (bg 0..15, j 0..31), 4 batches x 32-way K-split;
// wave halves read identical s_W addresses -> LDS broadcast (free).
__global__ void __launch_bounds__(512, 1)
k_enc(const int*   __restrict__ p_x,
      const float* __restrict__ p_eemb,
      const float* __restrict__ p_eWih, const float* __restrict__ p_eWhh,
      const float* __restrict__ p_ebih, const float* __restrict__ p_ebhh)
{
  __shared__ __align__(16) float s_W[8192];   // [16 rows][512]
  __shared__ float s_gat[1024];               // [16 rows][64 b]
  __shared__ float s_b[16];
  __shared__ int   s_len[64];

  const int w = blockIdx.x, tid = threadIdx.x;
  const int l = w >> 6, q = w & 63;            // layer, h-group (owns h 4q..4q+3)
  const int bg = tid >> 5, j = tid & 31;       // 4 batches/thread, 32-way K-split
  const int cb = (tid & 255) >> 2, ce = tid & 3;  // cell mapping (tid<256)

  for (int fi = tid; fi < 8192; fi += 512){
    int row = fi >> 9, k = fi & 511;
    int e = row >> 2, g = row & 3;
    int wrow = g*256 + 4*q + e;
    s_W[fi] = (k < 256) ? p_eWih[((size_t)l*1024 + wrow)*256 + k]
                        : p_eWhh[((size_t)l*1024 + wrow)*256 + (k - 256)];
  }
  if (tid < 16){
    int e = tid >> 2, g = tid & 3;
    int wrow = g*256 + 4*q + e;
    s_b[tid] = p_ebih[l*1024 + wrow] + p_ebhh[l*1024 + wrow];
  }
  if (tid < 64) s_len[tid] = g_len[tid];
  float c_reg = 0.f, h_frz = 0.f;
  __syncthreads();

  const int li = (q & 3) << 4;
  for (int t = 0; t < TT; ++t){
    // ---- R8-proven wait: own rel>=t, upstream rel>=t+1, backpressure rel>=t-3 ----
    if (tid == 0){
      for (;;){
        bool ok = (ldu(&g_erel[l][li]) >= (unsigned)t);
        if (ok && l > 0)               ok = (ldu(&g_erel[l-1][li]) >= (unsigned)(t+1));
        if (ok && l < 2 && t >= RING)  ok = (ldu(&g_erel[l+1][li]) >= (unsigned)(t-(RING-1)));
        if (ok) break;
        __builtin_amdgcn_s_sleep(1);
      }
    }
    __syncthreads();

    // ---- inputs: xin[bb][c]; c0,c1 = x halves; c2,c3 = own-h halves ----
    float4 xin[4][4];
    #pragma unroll
    for (int bb = 0; bb < 4; ++bb){
      const int batch = 4*bg + bb;
      if (l == 0){
        const float* xs = p_eemb + (size_t)p_x[batch*TT + t]*HH;
        xin[bb][0] = *(const float4*)(xs + 4*j);
        xin[bb][1] = *(const float4*)(xs + 128 + 4*j);
      } else {
        const float* xs = &g_hring[l-1][t & (RING-1)][batch][0];
        { float2 a = ld2(xs + 4*j),       c2 = ld2(xs + 4*j + 2);       xin[bb][0] = make_float4(a.x,a.y,c2.x,c2.y); }
        { float2 a = ld2(xs + 128 + 4*j), c2 = ld2(xs + 128 + 4*j + 2); xin[bb][1] = make_float4(a.x,a.y,c2.x,c2.y); }
      }
      const float* hs = &g_hring[l][(t + RING - 1) & (RING-1)][batch][0];
      { float2 a = ld2(hs + 4*j),       c2 = ld2(hs + 4*j + 2);       xin[bb][2] = make_float4(a.x,a.y,c2.x,c2.y); }
      { float2 a = ld2(hs + 128 + 4*j), c2 = ld2(hs + 128 + 4*j + 2); xin[bb][3] = make_float4(a.x,a.y,c2.x,c2.y); }
    }

    float acc[16][4];
    #pragma unroll
    for (int r = 0; r < 16; ++r){ acc[r][0]=0.f; acc[r][1]=0.f; acc[r][2]=0.f; acc[r][3]=0.f; }
    #pragma unroll
    for (int c = 0; c < 4; ++c){
      #pragma unroll
      for (int r = 0; r < 16; ++r){
        float4 wv = *(const float4*)&s_W[r*512 + c*128 + 4*j];
        #pragma unroll
        for (int bb = 0; bb < 4; ++bb) DOT4(acc[r][bb], xin[bb][c], wv);
      }
    }
    #pragma unroll
    for (int r = 0; r < 16; ++r){
      #pragma unroll
      for (int bb = 0; bb < 4; ++bb){
        float v = acc[r][bb];
        v += __shfl_xor(v,1); v += __shfl_xor(v,2); v += __shfl_xor(v,4);
        v += __shfl_xor(v,8); v += __shfl_xor(v,16);
        acc[r][bb] = v;
      }
    }
    if (j == 0){
      #pragma unroll
      for (int r = 0; r < 16; ++r){
        #pragma unroll
        for (int bb = 0; bb < 4; ++bb) s_gat[r*64 + 4*bg + bb] = acc[r][bb];
      }
    }
    __syncthreads();

    if (tid < 256){
      float iv = s_gat[(ce*4+0)*64 + cb] + s_b[ce*4+0];
      float fv = s_gat[(ce*4+1)*64 + cb] + s_b[ce*4+1];
      float gv = s_gat[(ce*4+2)*64 + cb] + s_b[ce*4+2];
      float ov = s_gat[(ce*4+3)*64 + cb] + s_b[ce*4+3];
      float c2 = sigf(fv)*c_reg + sigf(iv)*tanhf(gv);
      float h2 = sigf(ov)*tanhf(c2);
      bool valid = (t < s_len[cb]);
      if (valid) c_reg = c2;
      h_frz = valid ? h2 : h_frz;                        // freeze past length
      stc(&g_hring[l][t & (RING-1)][cb][4*q + ce], h_frz);
      if (l == 2) g_enchid[t][cb][4*q + ce] = valid ? h_frz : 0.f;
    }

    asm volatile("s_waitcnt vmcnt(0)" ::: "memory");
    __syncthreads();
    if (tid == 0) stu(&g_earr[l][q], (unsigned)(t+1));
    if (q == 0 && tid < 64){                             // R8-proven master-gather
      while (!__all(ldu(&g_earr[l][tid]) >= (unsigned)(t+1)))
        __builtin_amdgcn_s_sleep(1);
      if (tid < 4) stu(&g_erel[l][tid << 4], (unsigned)(t+1));
    }
    __syncthreads();
  }
  if (tid < 256) g_cfin[l][cb][4*q + ce] = c_reg;        // plain; kernel-end flush
}

// ---------------- k_kv: K/V projections + decoder state init ----------------
__global__ void __launch_bounds__(512)
k_kv(const float* __restrict__ p_Wk, const float* __restrict__ p_bk,
     const float* __restrict__ p_Wv, const float* __restrict__ p_bv)
{
  const int w = blockIdx.x, tid = threadIdx.x;
  {
    const int b3 = w >> 2, t0 = (w & 3) * 64;
    const int n1 = tid & 127, rq = tid >> 7;
    for (int p = 0; p < 4; ++p){
      const int n = p*128 + n1;
      const float* wrow = (n < 256) ? (p_Wk + (size_t)n*HH) : (p_Wv + (size_t)(n-256)*HH);
      const float bias  = (n < 256) ? p_bk[n] : p_bv[n-256];
      const float4* wr4 = (const float4*)wrow;
      const float* hb = &g_enchid[t0 + rq*16][b3][0];
      const float4* hr[16];
      #pragma unroll
      for (int r = 0; r < 16; ++r) hr[r] = (const float4*)(hb + (size_t)r*NB*HH);
      float a16[16];
      #pragma unroll
      for (int r = 0; r < 16; ++r) a16[r] = 0.f;
      for (int k4 = 0; k4 < 64; ++k4){
        float4 wv = wr4[k4];
        #pragma unroll
        for (int r = 0; r < 16; ++r){ float4 h4 = hr[r][k4]; DOT4(a16[r], h4, wv); }
      }
      float* orow = (n < 256) ? &g_kp[b3][t0 + rq*16][n] : &g_vp[b3][t0 + rq*16][n-256];
      #pragma unroll
      for (int r = 0; r < 16; ++r) orow[(size_t)r*HH] = a16[r] + bias;
    }
  }
  const int gidx = w*512 + tid;
  if (gidx < 49152){
    ((float*)g_cdec)[gidx] = ((const float*)g_cfin)[gidx];
    int l = gidx >> 14, rem = gidx & 16383;
    ((float*)g_hdec)[gidx] = g_hring[l][RING-1][rem >> 8][rem & 255];
  }
}

// ---------------- k_a: argmax-reduce + attention + z0 (64 WGs x 256) ----------------
__global__ void __launch_bounds__(256)
k_a(int st,
    const float* __restrict__ p_Wq, const float* __restrict__ p_bq,
    const float* __restrict__ p_Wo, const float* __restrict__ p_bo,
    const float* __restrict__ p_demb)
{
  __shared__ __align__(16) float s_hs[256];
  __shared__ __align__(16) float s_q[256];
  __shared__ __align__(16) float s_sc[256];
  __shared__ __align__(16) float s_at[256];
  __shared__ __align__(16) float s_ctx[256];
  __shared__ float s_rv[4]; __shared__ int s_ri[4];

  const int bA = blockIdx.x, tid = threadIdx.x;
  const int slot = st & 1;
  int tok = 0;                                           // SOS
  if (st > 0){
    float v = g_wmax[tid][bA]; int idx = g_wmaxi[tid][bA];
    #pragma unroll
    for (int m = 1; m < 64; m <<= 1){
      float ov = __shfl_xor(v, m); int oi = __shfl_xor(idx, m);
      if (ov > v || (ov == v && oi < idx)){ v = ov; idx = oi; }
    }
    if ((tid & 63) == 0){ s_rv[tid >> 6] = v; s_ri[tid >> 6] = idx; }
    __syncthreads();
    if (tid == 0){
      float bv = s_rv[0]; int bi = s_ri[0];
      for (int q2 = 1; q2 < 4; ++q2){
        float ov = s_rv[q2]; int oi = s_ri[q2];
        if (ov > bv || (ov == bv && oi < bi)){ bv = ov; bi = oi; }
      }
      s_ri[0] = bi;
    }
    __syncthreads();
    tok = s_ri[0];
  }
  s_hs[tid] = g_hdec[slot][0][bA][tid] + g_hdec[slot][1][bA][tid] + g_hdec[slot][2][bA][tid];
  __syncthreads();
  {                                                      // q = hsum @ Wq.T + bq
    float a = p_bq[tid];
    const float4* wr = (const float4*)(p_Wq + (size_t)tid*HH);
    #pragma unroll 8
    for (int k4 = 0; k4 < 64; ++k4){
      float4 wv = wr[k4]; float4 h4 = *(const float4*)&s_hs[k4*4]; DOT4(a, h4, wv);
    }
    s_q[tid] = a;
  }
  __syncthreads();
  {                                                      // scores
    float a = 0.f;
    const float4* kr = (const float4*)&g_kp[bA][tid][0];
    #pragma unroll 8
    for (int k4 = 0; k4 < 64; ++k4){
      float4 kv = kr[k4]; float4 q4 = *(const float4*)&s_q[k4*4]; DOT4(a, q4, kv);
    }
    s_sc[tid] = a * 0.0625f;                             // 1/sqrt(256)
  }
  __syncthreads();
  {                                                      // softmax
    float sv = s_sc[tid];
    float m2 = sv;
    #pragma unroll
    for (int m = 1; m < 64; m <<= 1) m2 = fmaxf(m2, __shfl_xor(m2, m));
    if ((tid & 63) == 0) s_rv[tid >> 6] = m2;
    __syncthreads();
    if (tid == 0){ float mm = s_rv[0]; for (int q2 = 1; q2 < 4; ++q2) mm = fmaxf(mm, s_rv[q2]); s_rv[0] = mm; }
    __syncthreads();
    const float mx = s_rv[0];
    float ev = expf(sv - mx);
    float ss = ev;
    #pragma unroll
    for (int m = 1; m < 64; m <<= 1) ss += __shfl_xor(ss, m);
    __syncthreads();
    if ((tid & 63) == 0) s_rv[tid >> 6] = ss;
    __syncthreads();
    if (tid == 0){ float t2 = 0.f; for (int q2 = 0; q2 < 4; ++q2) t2 += s_rv[q2]; s_rv[0] = t2; }
    __syncthreads();
    s_at[tid] = ev / s_rv[0];
  }
  __syncthreads();
  {                                                      // ctx = attn @ vp
    float a = 0.f;
    const float* vb = &g_vp[bA][0][tid];
    #pragma unroll 4
    for (int t4 = 0; t4 < 64; ++t4){
      float4 a4 = *(const float4*)&s_at[t4*4];
      a += a4.x*vb[(size_t)(t4*4+0)*HH] + a4.y*vb[(size_t)(t4*4+1)*HH]
         + a4.z*vb[(size_t)(t4*4+2)*HH] + a4.w*vb[(size_t)(t4*4+3)*HH];
    }
    s_ctx[tid] = a;
  }
  __syncthreads();
  {                                                      // ctx @ Wo.T + bo ; z0
    float a = p_bo[tid];
    const float4* wr = (const float4*)(p_Wo + (size_t)tid*HH);
    #pragma unroll 8
    for (int k4 = 0; k4 < 64; ++k4){
      float4 wv = wr[k4]; float4 c4 = *(const float4*)&s_ctx[k4*4]; DOT4(a, c4, wv);
    }
    g_z0[bA][256 + tid] = a;
    g_z0[bA][tid] = p_demb[(size_t)tok*HH + tid];
  }
}

// decoder LSTM gate GEMM: plain loads; K-permuted stride-36 LDS weights, base 0.
template<int NCB>
__device__ __forceinline__ void dec_gates_p(const float* sw, const float* i0, const float* i1,
                                            const float* i2, int j, float out4[4]){
  float a0=0.f, a1=0.f, a2=0.f, a3=0.f;
  const float* ips[3] = { i0, i1, i2 };
  #pragma unroll
  for (int cb = 0; cb < NCB; ++cb){
    float2 xin[16];
    #pragma unroll
    for (int u = 0; u < 16; ++u) xin[u] = *(const float2*)(ips[cb] + u*16 + 2*j);
    #pragma unroll
    for (int u2 = 0; u2 < 8; ++u2){
      float2 pa = xin[2*u2], pb = xin[2*u2+1];
      const float* wb = &sw[(((cb*4+0)*8+j)*36) + u2*4];
      float4 w0 = *(const float4*)(wb);
      float4 w1 = *(const float4*)(wb + 288);
      float4 w2 = *(const float4*)(wb + 576);
      float4 w3 = *(const float4*)(wb + 864);
      a0 += pa.x*w0.x + pa.y*w0.y + pb.x*w0.z + pb.y*w0.w;
      a1 += pa.x*w1.x + pa.y*w1.y + pb.x*w1.z + pb.y*w1.w;
      a2 += pa.x*w2.x + pa.y*w2.y + pb.x*w2.z + pb.y*w2.w;
      a3 += pa.x*w3.x + pa.y*w3.y + pb.x*w3.z + pb.y*w3.w;
    }
  }
  #pragma unroll
  for (int m = 1; m < 8; m <<= 1){
    a0 += __shfl_xor(a0, m); a1 += __shfl_xor(a1, m);
    a2 += __shfl_xor(a2, m); a3 += __shfl_xor(a3, m);
  }
  out4[0]=a0; out4[1]=a1; out4[2]=a2; out4[3]=a3;
}

// ---------------- k_b / k_c / k_d: one decoder LSTM layer each ----------------
__global__ void __launch_bounds__(512)
k_b(int st, const float* __restrict__ p_dWih0, const float* __restrict__ p_dWhh,
    const float* __restrict__ p_dbih, const float* __restrict__ p_dbhh)
{
  __shared__ __align__(16) float s_w[3456];
  __shared__ float s_bd[4];
  const int w = blockIdx.x, tid = threadIdx.x;
  const int b = tid >> 3, j = tid & 7;
  const int slot = st & 1, nxt = slot ^ 1;
  for (int fi = tid; fi < 3072; fi += 512){
    int g = fi / 768, k = fi % 768; int row = g*256 + w;
    float v = (k < 512) ? p_dWih0[(size_t)row*512 + k]
                        : p_dWhh[(size_t)row*HH + (k - 512)];
    int cb = k >> 8, kk = k & 255;
    s_w[(((cb*4 + g)*8 + ((kk & 15) >> 1))*36) + (((kk >> 4) << 1) | (kk & 1))] = v;
  }
  if (tid < 4) s_bd[tid] = p_dbih[tid*256 + w] + p_dbhh[tid*256 + w];
  __syncthreads();
  float g4[4];
  dec_gates_p<3>(s_w, &g_z0[b][0], &g_z0[b][256], &g_hdec[slot][0][b][0], j, g4);
  if (j == 0){
    float iv=g4[0]+s_bd[0], fv=g4[1]+s_bd[1], gv=g4[2]+s_bd[2], ov=g4[3]+s_bd[3];
    float c2 = sigf(fv)*g_cdec[0][b][w] + sigf(iv)*tanhf(gv);
    g_cdec[0][b][w] = c2;
    g_hdec[nxt][0][b][w] = sigf(ov)*tanhf(c2);
  }
}

__global__ void __launch_bounds__(512)
k_c(int st, const float* __restrict__ p_dWihR, const float* __restrict__ p_dWhh,
    const float* __restrict__ p_dbih, const float* __restrict__ p_dbhh)
{
  __shared__ __align__(16) float s_w[2304];
  __shared__ float s_bd[4];
  const int w = blockIdx.x, tid = threadIdx.x;
  const int b = tid >> 3, j = tid & 7;
  const int slot = st & 1, nxt = slot ^ 1;
  for (int fi = tid; fi < 2048; fi += 512){
    int g = fi / 512, k = fi % 512; int row = g*256 + w;
    float v = (k < 256) ? p_dWihR[(size_t)row*HH + k]
                        : p_dWhh[(size_t)(1024 + row)*HH + (k - 256)];
    int cb = k >> 8, kk = k & 255;
    s_w[(((cb*4 + g)*8 + ((kk & 15) >> 1))*36) + (((kk >> 4) << 1) | (kk & 1))] = v;
  }
  if (tid < 4) s_bd[tid] = p_dbih[1024 + tid*256 + w] + p_dbhh[1024 + tid*256 + w];
  __syncthreads();
  float g4[4];
  dec_gates_p<2>(s_w, &g_hdec[nxt][0][b][0], &g_hdec[slot][1][b][0], nullptr, j, g4);
  if (j == 0){
    float iv=g4[0]+s_bd[0], fv=g4[1]+s_bd[1], gv=g4[2]+s_bd[2], ov=g4[3]+s_bd[3];
    float c2 = sigf(fv)*g_cdec[1][b][w] + sigf(iv)*tanhf(gv);
    g_cdec[1][b][w] = c2;
    g_hdec[nxt][1][b][w] = sigf(ov)*tanhf(c2);
  }
}

__global__ void __launch_bounds__(512)
k_d(int st, const float* __restrict__ p_dWihR, const float* __restrict__ p_dWhh,
    const float* __restrict__ p_dbih, const float* __restrict__ p_dbhh)
{
  __shared__ __align__(16) float s_w[2304];
  __shared__ float s_bd[4];
  const int w = blockIdx.x, tid = threadIdx.x;
  const int b = tid >> 3, j = tid & 7;
  const int slot = st & 1, nxt = slot ^ 1;
  for (int fi = tid; fi < 2048; fi += 512){
    int g = fi / 512, k = fi % 512; int row = g*256 + w;
    float v = (k < 256) ? p_dWihR[(size_t)(1024 + row)*HH + k]
                        : p_dWhh[(size_t)(2048 + row)*HH + (k - 256)];
    int cb = k >> 8, kk = k & 255;
    s_w[(((cb*4 + g)*8 + ((kk & 15) >> 1))*36) + (((kk >> 4) << 1) | (kk & 1))] = v;
  }
  if (tid < 4) s_bd[tid] = p_dbih[2048 + tid*256 + w] + p_dbhh[2048 + tid*256 + w];
  __syncthreads();
  float g4[4];
  dec_gates_p<2>(s_w, &g_hdec[nxt][1][b][0], &g_hdec[slot][2][b][0], nullptr, j, g4);
  if (j == 0){
    float iv=g4[0]+s_bd[0], fv=g4[1]+s_bd[1], gv=g4[2]+s_bd[2], ov=g4[3]+s_bd[3];
    float c2 = sigf(fv)*g_cdec[2][b][w] + sigf(iv)*tanhf(gv);
    g_cdec[2][b][w] = c2;
    g_hdec[nxt][2][b][w] = sigf(ov)*tanhf(c2);
  }
}

// ---------------- k_e: logits GEMM + per-WG argmax candidates ----------------
__global__ void __launch_bounds__(512)
k_e(int st, const float* __restrict__ p_dW, const float* __restrict__ p_db,
    float* __restrict__ p_out)
{
  __shared__ __align__(16) float s_h2[NB*HH];
  const int w = blockIdx.x, tid = threadIdx.x;
  const int nxt = (st & 1) ^ 1;
  {
    const float4* src = (const float4*)&g_hdec[nxt][2][0][0];
    float4* dst = (float4*)s_h2;
    #pragma unroll
    for (int u = 0; u < 8; ++u){ int i4 = tid + 512*u; dst[i4] = src[i4]; }
  }
  __syncthreads();

  const int cs = tid & 63, qb = tid >> 6;          // qb = wave id; batches qb*8..qb*8+7
  const bool ok0 = (2*cs)   < 125;
  const bool ok1 = (2*cs+1) < 125;
  const int c0 = w*125 + 2*cs, c1 = c0 + 1;
  const float4* wr0 = (const float4*)(p_dW + (size_t)(ok0 ? c0 : w*125)*HH);
  const float4* wr1 = (const float4*)(p_dW + (size_t)(ok1 ? c1 : w*125)*HH);
  const float4* zr[8];
  #pragma unroll
  for (int r = 0; r < 8; ++r) zr[r] = (const float4*)&s_h2[(qb*8 + r)*HH];
  float a0[8], a1[8];
  #pragma unroll
  for (int r = 0; r < 8; ++r){ a0[r] = 0.f; a1[r] = 0.f; }
  for (int k4 = 0; k4 < 64; ++k4){
    float4 w0 = wr0[k4], w1 = wr1[k4];
    #pragma unroll
    for (int r = 0; r < 8; ++r){
      float4 z4 = zr[r][k4];
      DOT4(a0[r], z4, w0);
      DOT4(a1[r], z4, w1);
    }
  }
  const float bias0 = ok0 ? p_db[c0] : 0.f;
  const float bias1 = ok1 ? p_db[c1] : 0.f;
  #pragma unroll
  for (int r = 0; r < 8; ++r){
    const int bb = qb*8 + r;
    float val0 = a0[r] + bias0, val1 = a1[r] + bias1;
    float* orow = p_out + ((size_t)bb*NSTEP + st)*NCLS;
    if (ok0) orow[c0] = val0;
    if (ok1) orow[c1] = val1;
    float v = ok0 ? val0 : -1e38f;
    int idx  = ok0 ? c0 : 0x7fffffff;
    if (ok1 && val1 > v){ v = val1; idx = c1; }    // tie keeps c0 (lower index)
    #pragma unroll
    for (int m = 1; m < 64; m <<= 1){
      float ov = __shfl_xor(v, m); int oi = __shfl_xor(idx, m);
      if (ov > v || (ov == v && oi < idx)){ v = ov; idx = oi; }  // first-index tie-break
    }
    if (cs == 0){ g_wmax[w][bb] = v; g_wmaxi[w][bb] = idx; }
  }
}

extern "C" void kernel_launch(void* const* d_in, const int* in_sizes, int n_in,
                              void* d_out, int out_size, void* d_ws, size_t ws_size,
                              hipStream_t stream){
  (void)in_sizes; (void)n_in; (void)out_size; (void)d_ws; (void)ws_size;
  const int*   x     = (const int*)d_in[0];
  const float* eemb  = (const float*)d_in[2];
  const float* eWih  = (const float*)d_in[3];
  const float* eWhh  = (const float*)d_in[4];
  const float* ebih  = (const float*)d_in[5];
  const float* ebhh  = (const float*)d_in[6];
  const float* Wq    = (const float*)d_in[7];
  const float* bq    = (const float*)d_in[8];
  const float* Wk    = (const float*)d_in[9];
  const float* bk    = (const float*)d_in[10];
  const float* Wv    = (const float*)d_in[11];
  const float* bv    = (const float*)d_in[12];
  const float* Wo    = (const float*)d_in[13];
  const float* bo    = (const float*)d_in[14];
  const float* demb  = (const float*)d_in[15];
  const float* dWih0 = (const float*)d_in[16];
  const float* dWihR = (const float*)d_in[17];
  const float* dWhh  = (const float*)d_in[18];
  const float* dbih  = (const float*)d_in[19];
  const float* dbhh  = (const float*)d_in[20];
  const float* dW    = (const float*)d_in[21];
  const float* db    = (const float*)d_in[22];
  float* out = (float*)d_out;

  k_init<<<dim3(256), dim3(256), 0, stream>>>(x);
  k_enc<<<dim3(192), dim3(512), 0, stream>>>(x, eemb, eWih, eWhh, ebih, ebhh);
  k_kv<<<dim3(256), dim3(512), 0, stream>>>(Wk, bk, Wv, bv);
  for (int st = 0; st < NSTEP; ++st){
    k_a<<<dim3(64),  dim3(256), 0, stream>>>(st, Wq, bq, Wo, bo, demb);
    k_b<<<dim3(256), dim3(512), 0, stream>>>(st, dWih0, dWhh, dbih, dbhh);
    k_c<<<dim3(256), dim3(512), 0, stream>>>(st, dWihR, dWhh, dbih, dbhh);
    k_d<<<dim3(256), dim3(512), 0, stream>>>(st, dWihR, dWhh, dbih, dbhh);
    k_e<<<dim3(256), dim3(512), 0, stream>>>(st, dW, db, out);
  }
}

// Round 11
// 5719.151 us; speedup vs baseline: 1.3805x; 1.3805x over previous
//
#include <hip/hip_runtime.h>
#include <math.h>

// EncoderDecoderAttentionModel: B=64, T=256, H=D=256, L=3, NSTEPS=25, C=32000
#define TT    256
#define NB    64
#define HH    256
#define NSTEP 25
#define NCLS  32000
#define PADI  3
#define RING  4

// ---------------- static device scratch ----------------
__device__ __align__(16) float g_hring[3][RING][NB][HH]; // encoder h ring (sc1 in k_enc)
__device__ __align__(16) float g_enchid[TT][NB][HH];     // plain (cross-kernel)
__device__ __align__(16) float g_kp[NB][TT][HH];
__device__ __align__(16) float g_vp[NB][TT][HH];
__device__ __align__(16) float g_cfin[3][NB][HH];
__device__ __align__(16) float g_hdec[2][3][NB][HH];     // decoder h ping-pong (plain)
__device__ __align__(16) float g_cdec[3][NB][HH];        // decoder c state (plain)
__device__ __align__(16) float g_z0[NB][512];            // [unused ; ctx] (plain)
__device__ float    g_wmax[256][NB];
__device__ int      g_wmaxi[256][NB];
__device__ int      g_len[NB];
__device__ unsigned g_earr[3][64];                       // k_enc per-layer arrive flags
__device__ unsigned g_erel[3][64];                       // per-layer release, 4 lines at [l][16i]

__device__ __forceinline__ float sigf(float v){ return 1.0f / (1.0f + expf(-v)); }

#define SCOPE_AG __HIP_MEMORY_SCOPE_AGENT
typedef unsigned long long u64;
__device__ __forceinline__ float2 ld2(const float* p){
  u64 v = __hip_atomic_load((const u64*)p, __ATOMIC_RELAXED, SCOPE_AG);
  float2 r; __builtin_memcpy(&r, &v, 8); return r;
}
__device__ __forceinline__ void  stc(float* p, float v){ __hip_atomic_store(p, v, __ATOMIC_RELAXED, SCOPE_AG); }
__device__ __forceinline__ unsigned ldu(const unsigned* p){ return __hip_atomic_load(p, __ATOMIC_RELAXED, SCOPE_AG); }
__device__ __forceinline__ void  stu(unsigned* p, unsigned v){ __hip_atomic_store(p, v, __ATOMIC_RELAXED, SCOPE_AG); }

#define DOT4(a_, x_, w_) (a_) += (x_).x*(w_).x + (x_).y*(w_).y + (x_).z*(w_).z + (x_).w*(w_).w

// ---------------- k_init: flags, ring seed, lengths ----------------
__global__ void __launch_bounds__(256) k_init(const int* __restrict__ p_x){
  const int blk = blockIdx.x, tid = threadIdx.x;
  if (blk < 192){
    int idx = blk*256 + tid;                 // 49152 = 3*64*256 (ring slot RING-1)
    int l = idx >> 14, rem = idx & 16383;
    g_hring[l][RING-1][rem >> 8][rem & 255] = 0.f;
  } else {
    __shared__ int s_c[4];
    int b = blk - 192;
    int cnt = (p_x[b*TT + tid] != PADI) ? 1 : 0;
    #pragma unroll
    for (int m = 1; m < 64; m <<= 1) cnt += __shfl_xor(cnt, m);
    if ((tid & 63) == 0) s_c[tid >> 6] = cnt;
    __syncthreads();
    if (tid == 0) g_len[b] = s_c[0] + s_c[1] + s_c[2] + s_c[3];
  }
  if (blk == 0 && tid < 192){
    ((unsigned*)g_earr)[tid] = 0u;
    ((unsigned*)g_erel)[tid] = 0u;
  }
}

// ---------------- k_enc: R8-verbatim 3-layer pipelined encoder ----------------
__global__ void __launch_bounds__(512, 1)
k_enc(const int*   __restrict__ p_x,
      const float* __restrict__ p_eemb,
      const float* __restrict__ p_eWih, const float* __restrict__ p_eWhh,
      const float* __restrict__ p_ebih, const float* __restrict__ p_ebhh)
{
  __shared__ __align__(16) float s_W[8192];   // [16 rows][512] identity layout
  __shared__ float s_gat[1024];               // [16 rows][64 b]
  __shared__ float s_b[16];
  __shared__ int   s_len[64];

  const int w = blockIdx.x, tid = threadIdx.x;
  const int l = w >> 6, q = w & 63;           // layer, h-group (owns h 4q..4q+3)
  const int b2 = tid >> 4, j = tid & 15;      // 2 batches/thread, 16-way K-split
  const int ce = tid >> 6, cb = tid & 63;     // cell-update mapping (tid<256)

  for (int fi = tid; fi < 8192; fi += 512){
    int row = fi >> 9, k = fi & 511;
    int e = row >> 2, g = row & 3;
    int wrow = g*256 + 4*q + e;
    s_W[fi] = (k < 256) ? p_eWih[((size_t)l*1024 + wrow)*256 + k]
                        : p_eWhh[((size_t)l*1024 + wrow)*256 + (k - 256)];
  }
  if (tid < 16){
    int e = tid >> 2, g = tid & 3;
    int wrow = g*256 + 4*q + e;
    s_b[tid] = p_ebih[l*1024 + wrow] + p_ebhh[l*1024 + wrow];
  }
  if (tid < 64) s_len[tid] = g_len[tid];
  float c_reg = 0.f, h_frz = 0.f;
  __syncthreads();

  const int li = (q & 3) << 4;
  for (int t = 0; t < TT; ++t){
    // waits: own rel>=t, upstream rel>=t+1, downstream backpressure rel>=t-3
    if (tid == 0){
      for (;;){
        bool ok = (ldu(&g_erel[l][li]) >= (unsigned)t);
        if (ok && l > 0)               ok = (ldu(&g_erel[l-1][li]) >= (unsigned)(t+1));
        if (ok && l < 2 && t >= RING)  ok = (ldu(&g_erel[l+1][li]) >= (unsigned)(t-(RING-1)));
        if (ok) break;
        __builtin_amdgcn_s_sleep(1);
      }
    }
    __syncthreads();

    // inputs: x-slice (embed or below-layer h) + own-layer h[t-1]
    float4 xin[2][4], hin[2][4];
    #pragma unroll
    for (int bb = 0; bb < 2; ++bb){
      const int batch = 2*b2 + bb;
      if (l == 0){
        const float* xs = p_eemb + (size_t)p_x[batch*TT + t]*HH;
        #pragma unroll
        for (int u = 0; u < 4; ++u) xin[bb][u] = *(const float4*)(xs + u*64 + 4*j);
      } else {
        const float* xs = &g_hring[l-1][t & (RING-1)][batch][0];
        #pragma unroll
        for (int u = 0; u < 4; ++u){
          float2 a = ld2(xs + u*64 + 4*j), c = ld2(xs + u*64 + 4*j + 2);
          xin[bb][u] = make_float4(a.x, a.y, c.x, c.y);
        }
      }
      const float* hs = &g_hring[l][(t + RING - 1) & (RING-1)][batch][0];
      #pragma unroll
      for (int u = 0; u < 4; ++u){
        float2 a = ld2(hs + u*64 + 4*j), c = ld2(hs + u*64 + 4*j + 2);
        hin[bb][u] = make_float4(a.x, a.y, c.x, c.y);
      }
    }

    float acc[16][2];
    #pragma unroll
    for (int r = 0; r < 16; ++r){ acc[r][0] = 0.f; acc[r][1] = 0.f; }
    #pragma unroll
    for (int u = 0; u < 8; ++u){
      float4 i0 = (u < 4) ? xin[0][u] : hin[0][u-4];
      float4 i1 = (u < 4) ? xin[1][u] : hin[1][u-4];
      #pragma unroll
      for (int row = 0; row < 16; ++row){
        float4 wv = *(const float4*)&s_W[row*512 + u*64 + 4*j];
        DOT4(acc[row][0], i0, wv);
        DOT4(acc[row][1], i1, wv);
      }
    }
    #pragma unroll
    for (int row = 0; row < 16; ++row){
      #pragma unroll
      for (int bb = 0; bb < 2; ++bb){
        float v = acc[row][bb];
        v += __shfl_xor(v, 1); v += __shfl_xor(v, 2);
        v += __shfl_xor(v, 4); v += __shfl_xor(v, 8);
        acc[row][bb] = v;
      }
    }
    if (j == 0){
      #pragma unroll
      for (int row = 0; row < 16; ++row){
        s_gat[row*64 + 2*b2    ] = acc[row][0];
        s_gat[row*64 + 2*b2 + 1] = acc[row][1];
      }
    }
    __syncthreads();

    if (tid < 256){
      float iv = s_gat[(ce*4+0)*64 + cb] + s_b[ce*4+0];
      float fv = s_gat[(ce*4+1)*64 + cb] + s_b[ce*4+1];
      float gv = s_gat[(ce*4+2)*64 + cb] + s_b[ce*4+2];
      float ov = s_gat[(ce*4+3)*64 + cb] + s_b[ce*4+3];
      float c2 = sigf(fv)*c_reg + sigf(iv)*tanhf(gv);
      float h2 = sigf(ov)*tanhf(c2);
      bool valid = (t < s_len[cb]);
      if (valid) c_reg = c2;
      h_frz = valid ? h2 : h_frz;
      stc(&g_hring[l][t & (RING-1)][cb][4*q + ce], h_frz);
      if (l == 2) g_enchid[t][cb][4*q + ce] = valid ? h_frz : 0.f;  // plain
    }

    asm volatile("s_waitcnt vmcnt(0)" ::: "memory");
    __syncthreads();
    if (tid == 0) stu(&g_earr[l][q], (unsigned)(t+1));
    if (q == 0 && tid < 64){
      while (!__all(ldu(&g_earr[l][tid]) >= (unsigned)(t+1)))
        __builtin_amdgcn_s_sleep(1);
      if (tid < 4) stu(&g_erel[l][tid << 4], (unsigned)(t+1));
    }
    __syncthreads();
  }
  if (tid < 256) g_cfin[l][cb][4*q + ce] = c_reg;   // plain; kernel-end flush
}

// ---------------- k_kv: K/V projections + decoder state init ----------------
__global__ void __launch_bounds__(512)
k_kv(const float* __restrict__ p_Wk, const float* __restrict__ p_bk,
     const float* __restrict__ p_Wv, const float* __restrict__ p_bv)
{
  const int w = blockIdx.x, tid = threadIdx.x;
  {
    const int b3 = w >> 2, t0 = (w & 3) * 64;
    const int n1 = tid & 127, rq = tid >> 7;
    for (int p = 0; p < 4; ++p){
      const int n = p*128 + n1;
      const float* wrow = (n < 256) ? (p_Wk + (size_t)n*HH) : (p_Wv + (size_t)(n-256)*HH);
      const float bias  = (n < 256) ? p_bk[n] : p_bv[n-256];
      const float4* wr4 = (const float4*)wrow;
      const float* hb = &g_enchid[t0 + rq*16][b3][0];
      const float4* hr[16];
      #pragma unroll
      for (int r = 0; r < 16; ++r) hr[r] = (const float4*)(hb + (size_t)r*NB*HH);
      float a16[16];
      #pragma unroll
      for (int r = 0; r < 16; ++r) a16[r] = 0.f;
      for (int k4 = 0; k4 < 64; ++k4){
        float4 wv = wr4[k4];
        #pragma unroll
        for (int r = 0; r < 16; ++r){ float4 h4 = hr[r][k4]; DOT4(a16[r], h4, wv); }
      }
      float* orow = (n < 256) ? &g_kp[b3][t0 + rq*16][n] : &g_vp[b3][t0 + rq*16][n-256];
      #pragma unroll
      for (int r = 0; r < 16; ++r) orow[(size_t)r*HH] = a16[r] + bias;
    }
  }
  const int gidx = w*512 + tid;
  if (gidx < 49152){
    ((float*)g_cdec)[gidx] = ((const float*)g_cfin)[gidx];
    int l = gidx >> 14, rem = gidx & 16383;
    ((float*)g_hdec)[gidx] = g_hring[l][RING-1][rem >> 8][rem & 255];
  }
}

// ---------------- attention device routine (256 threads; writes z0 ctx) ----------------
__device__ __forceinline__ void attn_body(int bA, int aslot, int tid,
    const float* p_Wq, const float* p_bq, const float* p_Wo, const float* p_bo,
    float* s_hs, float* s_q, float* s_sc, float* s_at, float* s_ctx, float* s_rv)
{
  if (tid < 256)
    s_hs[tid] = g_hdec[aslot][0][bA][tid] + g_hdec[aslot][1][bA][tid] + g_hdec[aslot][2][bA][tid];
  __syncthreads();
  if (tid < 256){                                // q = hsum @ Wq.T + bq
    float a = p_bq[tid];
    const float4* wr = (const float4*)(p_Wq + (size_t)tid*HH);
    #pragma unroll 8
    for (int k4 = 0; k4 < 64; ++k4){
      float4 wv = wr[k4]; float4 h4 = *(const float4*)&s_hs[k4*4]; DOT4(a, h4, wv);
    }
    s_q[tid] = a;
  }
  __syncthreads();
  if (tid < 256){                                // scores
    float a = 0.f;
    const float4* kr = (const float4*)&g_kp[bA][tid][0];
    #pragma unroll 8
    for (int k4 = 0; k4 < 64; ++k4){
      float4 kv = kr[k4]; float4 q4 = *(const float4*)&s_q[k4*4]; DOT4(a, q4, kv);
    }
    s_sc[tid] = a * 0.0625f;                     // 1/sqrt(256)
  }
  __syncthreads();
  {                                              // softmax
    float sv = (tid < 256) ? s_sc[tid] : -1e38f;
    float m2 = sv;
    #pragma unroll
    for (int m = 1; m < 64; m <<= 1) m2 = fmaxf(m2, __shfl_xor(m2, m));
    if ((tid & 63) == 0 && tid < 256) s_rv[tid >> 6] = m2;
    __syncthreads();
    if (tid == 0){ float mm = s_rv[0]; for (int q2 = 1; q2 < 4; ++q2) mm = fmaxf(mm, s_rv[q2]); s_rv[0] = mm; }
    __syncthreads();
    const float mx = s_rv[0];
    float ev = (tid < 256) ? expf(sv - mx) : 0.f;
    float ss = ev;
    #pragma unroll
    for (int m = 1; m < 64; m <<= 1) ss += __shfl_xor(ss, m);
    __syncthreads();
    if ((tid & 63) == 0 && tid < 256) s_rv[tid >> 6] = ss;
    __syncthreads();
    if (tid == 0){ float t2 = 0.f; for (int q2 = 0; q2 < 4; ++q2) t2 += s_rv[q2]; s_rv[0] = t2; }
    __syncthreads();
    if (tid < 256) s_at[tid] = ev / s_rv[0];
  }
  __syncthreads();
  if (tid < 256){                                // ctx = attn @ vp
    float a = 0.f;
    const float* vb = &g_vp[bA][0][tid];
    #pragma unroll 4
    for (int t4 = 0; t4 < 64; ++t4){
      float4 a4 = *(const float4*)&s_at[t4*4];
      a += a4.x*vb[(size_t)(t4*4+0)*HH] + a4.y*vb[(size_t)(t4*4+1)*HH]
         + a4.z*vb[(size_t)(t4*4+2)*HH] + a4.w*vb[(size_t)(t4*4+3)*HH];
    }
    s_ctx[tid] = a;
  }
  __syncthreads();
  if (tid < 256){                                // ctx @ Wo.T + bo -> z0 ctx half
    float a = p_bo[tid];
    const float4* wr = (const float4*)(p_Wo + (size_t)tid*HH);
    #pragma unroll 8
    for (int k4 = 0; k4 < 64; ++k4){
      float4 wv = wr[k4]; float4 c4 = *(const float4*)&s_ctx[k4*4]; DOT4(a, c4, wv);
    }
    g_z0[bA][256 + tid] = a;
  }
}

// ---------------- k_att: prologue attention for step 0 ----------------
__global__ void __launch_bounds__(256)
k_att(int aslot, const float* __restrict__ p_Wq, const float* __restrict__ p_bq,
      const float* __restrict__ p_Wo, const float* __restrict__ p_bo)
{
  __shared__ __align__(16) float s_hs[256], s_q[256], s_sc[256], s_at[256], s_ctx[256];
  __shared__ float s_rv[4];
  attn_body(blockIdx.x, aslot, threadIdx.x, p_Wq, p_bq, p_Wo, p_bo,
            s_hs, s_q, s_sc, s_at, s_ctx, s_rv);
}

// decoder LSTM gate GEMM: plain loads; K-permuted stride-36 LDS weights, base 0.
template<int NCB>
__device__ __forceinline__ void dec_gates_p(const float* sw, const float* i0, const float* i1,
                                            const float* i2, int j, float out4[4]){
  float a0=0.f, a1=0.f, a2=0.f, a3=0.f;
  const float* ips[3] = { i0, i1, i2 };
  #pragma unroll
  for (int cb = 0; cb < NCB; ++cb){
    float2 xin[16];
    #pragma unroll
    for (int u = 0; u < 16; ++u) xin[u] = *(const float2*)(ips[cb] + u*16 + 2*j);
    #pragma unroll
    for (int u2 = 0; u2 < 8; ++u2){
      float2 pa = xin[2*u2], pb = xin[2*u2+1];
      const float* wb = &sw[(((cb*4+0)*8+j)*36) + u2*4];
      float4 w0 = *(const float4*)(wb);
      float4 w1 = *(const float4*)(wb + 288);
      float4 w2 = *(const float4*)(wb + 576);
      float4 w3 = *(const float4*)(wb + 864);
      a0 += pa.x*w0.x + pa.y*w0.y + pb.x*w0.z + pb.y*w0.w;
      a1 += pa.x*w1.x + pa.y*w1.y + pb.x*w1.z + pb.y*w1.w;
      a2 += pa.x*w2.x + pa.y*w2.y + pb.x*w2.z + pb.y*w2.w;
      a3 += pa.x*w3.x + pa.y*w3.y + pb.x*w3.z + pb.y*w3.w;
    }
  }
  #pragma unroll
  for (int m = 1; m < 8; m <<= 1){
    a0 += __shfl_xor(a0, m); a1 += __shfl_xor(a1, m);
    a2 += __shfl_xor(a2, m); a3 += __shfl_xor(a3, m);
  }
  out4[0]=a0; out4[1]=a1; out4[2]=a2; out4[3]=a3;
}

// ---------------- k_bt: argmax-reduce + embed-gather + decoder layer 0 ----------------
__global__ void __launch_bounds__(512)
k_bt(int st, const float* __restrict__ p_demb,
     const float* __restrict__ p_dWih0, const float* __restrict__ p_dWhh,
     const float* __restrict__ p_dbih,  const float* __restrict__ p_dbhh)
{
  __shared__ __align__(16) float s_w[3456];
  __shared__ float s_bd[4];
  __shared__ int   s_tok[64];
  const int w = blockIdx.x, tid = threadIdx.x;
  const int b = tid >> 3, j = tid & 7;
  const int slot = st & 1, nxt = slot ^ 1;
  for (int fi = tid; fi < 3072; fi += 512){
    int g = fi / 768, k = fi % 768; int row = g*256 + w;
    float v = (k < 512) ? p_dWih0[(size_t)row*512 + k]
                        : p_dWhh[(size_t)row*HH + (k - 512)];
    int cb = k >> 8, kk = k & 255;
    s_w[(((cb*4 + g)*8 + ((kk & 15) >> 1))*36) + (((kk >> 4) << 1) | (kk & 1))] = v;
  }
  if (tid < 4) s_bd[tid] = p_dbih[tid*256 + w] + p_dbhh[tid*256 + w];

  if (st > 0){                                   // per-WG redundant argmax over candidates
    float v = -1e38f; int idx = 0x7fffffff;
    #pragma unroll 4
    for (int i = 0; i < 32; ++i){
      int c = j*32 + i;
      float cv = g_wmax[c][b]; int ci = g_wmaxi[c][b];
      if (cv > v || (cv == v && ci < idx)){ v = cv; idx = ci; }
    }
    #pragma unroll
    for (int m = 1; m < 8; m <<= 1){             // reduce across the 8 j-lanes
      float ov = __shfl_xor(v, m); int oi = __shfl_xor(idx, m);
      if (ov > v || (ov == v && oi < idx)){ v = ov; idx = oi; }
    }
    if (j == 0) s_tok[b] = idx;
  } else {
    if (tid < 64) s_tok[tid] = 0;                // SOS
  }
  __syncthreads();

  const float* e0 = p_demb + (size_t)s_tok[b]*HH;  // embed row read directly as gate input
  float g4[4];
  dec_gates_p<3>(s_w, e0, &g_z0[b][256], &g_hdec[slot][0][b][0], j, g4);
  if (j == 0){
    float iv=g4[0]+s_bd[0], fv=g4[1]+s_bd[1], gv=g4[2]+s_bd[2], ov=g4[3]+s_bd[3];
    float c2 = sigf(fv)*g_cdec[0][b][w] + sigf(iv)*tanhf(gv);
    g_cdec[0][b][w] = c2;
    g_hdec[nxt][0][b][w] = sigf(ov)*tanhf(c2);
  }
}

// ---------------- k_c / k_d: decoder layers 1,2 ----------------
__global__ void __launch_bounds__(512)
k_c(int st, const float* __restrict__ p_dWihR, const float* __restrict__ p_dWhh,
    const float* __restrict__ p_dbih, const float* __restrict__ p_dbhh)
{
  __shared__ __align__(16) float s_w[2304];
  __shared__ float s_bd[4];
  const int w = blockIdx.x, tid = threadIdx.x;
  const int b = tid >> 3, j = tid & 7;
  const int slot = st & 1, nxt = slot ^ 1;
  for (int fi = tid; fi < 2048; fi += 512){
    int g = fi / 512, k = fi % 512; int row = g*256 + w;
    float v = (k < 256) ? p_dWihR[(size_t)row*HH + k]
                        : p_dWhh[(size_t)(1024 + row)*HH + (k - 256)];
    int cb = k >> 8, kk = k & 255;
    s_w[(((cb*4 + g)*8 + ((kk & 15) >> 1))*36) + (((kk >> 4) << 1) | (kk & 1))] = v;
  }
  if (tid < 4) s_bd[tid] = p_dbih[1024 + tid*256 + w] + p_dbhh[1024 + tid*256 + w];
  __syncthreads();
  float g4[4];
  dec_gates_p<2>(s_w, &g_hdec[nxt][0][b][0], &g_hdec[slot][1][b][0], nullptr, j, g4);
  if (j == 0){
    float iv=g4[0]+s_bd[0], fv=g4[1]+s_bd[1], gv=g4[2]+s_bd[2], ov=g4[3]+s_bd[3];
    float c2 = sigf(fv)*g_cdec[1][b][w] + sigf(iv)*tanhf(gv);
    g_cdec[1][b][w] = c2;
    g_hdec[nxt][1][b][w] = sigf(ov)*tanhf(c2);
  }
}

__global__ void __launch_bounds__(512)
k_d(int st, const float* __restrict__ p_dWihR, const float* __restrict__ p_dWhh,
    const float* __restrict__ p_dbih, const float* __restrict__ p_dbhh)
{
  __shared__ __align__(16) float s_w[2304];
  __shared__ float s_bd[4];
  const int w = blockIdx.x, tid = threadIdx.x;
  const int b = tid >> 3, j = tid & 7;
  const int slot = st & 1, nxt = slot ^ 1;
  for (int fi = tid; fi < 2048; fi += 512){
    int g = fi / 512, k = fi % 512; int row = g*256 + w;
    float v = (k < 256) ? p_dWihR[(size_t)(1024 + row)*HH + k]
                        : p_dWhh[(size_t)(2048 + row)*HH + (k - 256)];
    int cb = k >> 8, kk = k & 255;
    s_w[(((cb*4 + g)*8 + ((kk & 15) >> 1))*36) + (((kk >> 4) << 1) | (kk & 1))] = v;
  }
  if (tid < 4) s_bd[tid] = p_dbih[2048 + tid*256 + w] + p_dbhh[2048 + tid*256 + w];
  __syncthreads();
  float g4[4];
  dec_gates_p<2>(s_w, &g_hdec[nxt][1][b][0], &g_hdec[slot][2][b][0], nullptr, j, g4);
  if (j == 0){
    float iv=g4[0]+s_bd[0], fv=g4[1]+s_bd[1], gv=g4[2]+s_bd[2], ov=g4[3]+s_bd[3];
    float c2 = sigf(fv)*g_cdec[2][b][w] + sigf(iv)*tanhf(gv);
    g_cdec[2][b][w] = c2;
    g_hdec[nxt][2][b][w] = sigf(ov)*tanhf(c2);
  }
}

// ---------------- k_e2: logits GEMM + candidates (WGs 0-255) ∥ attention for next step (WGs 256-319) ----------------
__global__ void __launch_bounds__(512)
k_e2(int st, int aslot,
     const float* __restrict__ p_dW, const float* __restrict__ p_db,
     const float* __restrict__ p_Wq, const float* __restrict__ p_bq,
     const float* __restrict__ p_Wo, const float* __restrict__ p_bo,
     float* __restrict__ p_out)
{
  __shared__ __align__(16) float s_h2[NB*HH];    // logits path (32KB); attn path reuses prefix
  const int w = blockIdx.x, tid = threadIdx.x;

  if (w >= 256){                                 // attention for step st+1 (slot aslot)
    float* s_hs  = s_h2;
    float* s_q   = s_h2 + 256;
    float* s_sc  = s_h2 + 512;
    float* s_at  = s_h2 + 768;
    float* s_ctx = s_h2 + 1024;
    float* s_rv  = s_h2 + 1280;
    attn_body(w - 256, aslot, tid, p_Wq, p_bq, p_Wo, p_bo,
              s_hs, s_q, s_sc, s_at, s_ctx, s_rv);
    return;
  }

  {
    const float4* src = (const float4*)&g_hdec[aslot][2][0][0];   // aslot == nxt of step st
    float4* dst = (float4*)s_h2;
    #pragma unroll
    for (int u = 0; u < 8; ++u){ int i4 = tid + 512*u; dst[i4] = src[i4]; }
  }
  __syncthreads();

  const int cs = tid & 63, qb = tid >> 6;        // qb = wave id; batches qb*8..qb*8+7
  const bool ok0 = (2*cs)   < 125;
  const bool ok1 = (2*cs+1) < 125;
  const int c0 = w*125 + 2*cs, c1 = c0 + 1;
  const float4* wr0 = (const float4*)(p_dW + (size_t)(ok0 ? c0 : w*125)*HH);
  const float4* wr1 = (const float4*)(p_dW + (size_t)(ok1 ? c1 : w*125)*HH);
  const float4* zr[8];
  #pragma unroll
  for (int r = 0; r < 8; ++r) zr[r] = (const float4*)&s_h2[(qb*8 + r)*HH];
  float a0[8], a1[8];
  #pragma unroll
  for (int r = 0; r < 8; ++r){ a0[r] = 0.f; a1[r] = 0.f; }
  for (int k4 = 0; k4 < 64; ++k4){
    float4 w0 = wr0[k4], w1 = wr1[k4];
    #pragma unroll
    for (int r = 0; r < 8; ++r){
      float4 z4 = zr[r][k4];
      DOT4(a0[r], z4, w0);
      DOT4(a1[r], z4, w1);
    }
  }
  const float bias0 = ok0 ? p_db[c0] : 0.f;
  const float bias1 = ok1 ? p_db[c1] : 0.f;
  #pragma unroll
  for (int r = 0; r < 8; ++r){
    const int bb = qb*8 + r;
    float val0 = a0[r] + bias0, val1 = a1[r] + bias1;
    float* orow = p_out + ((size_t)bb*NSTEP + st)*NCLS;
    if (ok0) orow[c0] = val0;
    if (ok1) orow[c1] = val1;
    float v = ok0 ? val0 : -1e38f;
    int idx  = ok0 ? c0 : 0x7fffffff;
    if (ok1 && val1 > v){ v = val1; idx = c1; }  // tie keeps c0 (lower index)
    #pragma unroll
    for (int m = 1; m < 64; m <<= 1){
      float ov = __shfl_xor(v, m); int oi = __shfl_xor(idx, m);
      if (ov > v || (ov == v && oi < idx)){ v = ov; idx = oi; }  // first-index tie-break
    }
    if (cs == 0){ g_wmax[w][bb] = v; g_wmaxi[w][bb] = idx; }
  }
}

extern "C" void kernel_launch(void* const* d_in, const int* in_sizes, int n_in,
                              void* d_out, int out_size, void* d_ws, size_t ws_size,
                              hipStream_t stream){
  (void)in_sizes; (void)n_in; (void)out_size; (void)d_ws; (void)ws_size;
  const int*   x     = (const int*)d_in[0];
  const float* eemb  = (const float*)d_in[2];
  const float* eWih  = (const float*)d_in[3];
  const float* eWhh  = (const float*)d_in[4];
  const float* ebih  = (const float*)d_in[5];
  const float* ebhh  = (const float*)d_in[6];
  const float* Wq    = (const float*)d_in[7];
  const float* bq    = (const float*)d_in[8];
  const float* Wk    = (const float*)d_in[9];
  const float* bk    = (const float*)d_in[10];
  const float* Wv    = (const float*)d_in[11];
  const float* bv    = (const float*)d_in[12];
  const float* Wo    = (const float*)d_in[13];
  const float* bo    = (const float*)d_in[14];
  const float* demb  = (const float*)d_in[15];
  const float* dWih0 = (const float*)d_in[16];
  const float* dWihR = (const float*)d_in[17];
  const float* dWhh  = (const float*)d_in[18];
  const float* dbih  = (const float*)d_in[19];
  const float* dbhh  = (const float*)d_in[20];
  const float* dW    = (const float*)d_in[21];
  const float* db    = (const float*)d_in[22];
  float* out = (float*)d_out;

  k_init<<<dim3(256), dim3(256), 0, stream>>>(x);
  k_enc<<<dim3(192), dim3(512), 0, stream>>>(x, eemb, eWih, eWhh, ebih, ebhh);
  k_kv<<<dim3(256), dim3(512), 0, stream>>>(Wk, bk, Wv, bv);
  k_att<<<dim3(64), dim3(256), 0, stream>>>(0, Wq, bq, Wo, bo);
  for (int st = 0; st < NSTEP; ++st){
    const int aslot = (st & 1) ^ 1;
    k_bt<<<dim3(256), dim3(512), 0, stream>>>(st, demb, dWih0, dWhh, dbih, dbhh);
    k_c <<<dim3(256), dim3(512), 0, stream>>>(st, dWihR, dWhh, dbih, dbhh);
    k_d <<<dim3(256), dim3(512), 0, stream>>>(st, dWihR, dWhh, dbih, dbhh);
    k_e2<<<dim3(320), dim3(512), 0, stream>>>(st, aslot, dW, db, Wq, bq, Wo, bo, out);
  }
}